// Round 1
// baseline (398.052 us; speedup 1.0000x reference)
//
#include <hip/hip_runtime.h>
#include <math.h>

#define IMG_H 1080
#define IMG_W 1920
#define NFLOW 5
#define HW (IMG_H * IMG_W)

// Kernel 1: per-flow sum of squared error between frame2 and trunc(warp(frame1, flow_n))
__global__ __launch_bounds__(256) void psnr_partial_kernel(
    const float* __restrict__ flow,   // [N][H][W][2]
    const float* __restrict__ f1,     // [3][H][W]
    const float* __restrict__ f2,     // [3][H][W]
    float* __restrict__ sums)         // [N] (pre-zeroed)
{
    float acc[NFLOW];
#pragma unroll
    for (int n = 0; n < NFLOW; ++n) acc[n] = 0.0f;

    const int tid = blockIdx.x * blockDim.x + threadIdx.x;
    const int stride = gridDim.x * blockDim.x;

    for (int p = tid; p < HW; p += stride) {
        const int h = p / IMG_W;
        const int w = p - h * IMG_W;
        const float r0 = f2[p];
        const float r1 = f2[HW + p];
        const float r2 = f2[2 * HW + p];

#pragma unroll
        for (int n = 0; n < NFLOW; ++n) {
            const float2 fl = ((const float2*)flow)[n * HW + p];
            const float px = (float)w + fl.x;
            const float py = (float)h + fl.y;
            const float x0f = floorf(px);
            const float y0f = floorf(py);
            const float wx1 = px - x0f;
            const float wy1 = py - y0f;
            const float wx0 = 1.0f - wx1;
            const float wy0 = 1.0f - wy1;
            const float x1f = x0f + 1.0f;
            const float y1f = y0f + 1.0f;

            const bool vx0 = (x0f >= 0.0f) && (x0f <= (float)(IMG_W - 1));
            const bool vx1 = (x1f >= 0.0f) && (x1f <= (float)(IMG_W - 1));
            const bool vy0 = (y0f >= 0.0f) && (y0f <= (float)(IMG_H - 1));
            const bool vy1 = (y1f >= 0.0f) && (y1f <= (float)(IMG_H - 1));

            const int x0 = (int)fminf(fmaxf(x0f, 0.0f), (float)(IMG_W - 1));
            const int x1 = (int)fminf(fmaxf(x1f, 0.0f), (float)(IMG_W - 1));
            const int y0 = (int)fminf(fmaxf(y0f, 0.0f), (float)(IMG_H - 1));
            const int y1 = (int)fminf(fmaxf(y1f, 0.0f), (float)(IMG_H - 1));

            const int i00 = y0 * IMG_W + x0;
            const int i10 = y0 * IMG_W + x1;
            const int i01 = y1 * IMG_W + x0;
            const int i11 = y1 * IMG_W + x1;

            // fold per-tap validity into the bilinear weight (value*valid*weight)
            const float w00 = (vx0 && vy0) ? (wx0 * wy0) : 0.0f;
            const float w10 = (vx1 && vy0) ? (wx1 * wy0) : 0.0f;
            const float w01 = (vx0 && vy1) ? (wx0 * wy1) : 0.0f;
            const float w11 = (vx1 && vy1) ? (wx1 * wy1) : 0.0f;

            float a = 0.0f;
#pragma unroll
            for (int c = 0; c < 3; ++c) {
                const float* plane = f1 + c * HW;
                const float est = plane[i00] * w00 + plane[i10] * w10 +
                                  plane[i01] * w01 + plane[i11] * w11;
                const float e = truncf(est);
                const float r = (c == 0) ? r0 : ((c == 1) ? r1 : r2);
                const float d = r - e;
                a += d * d;
            }
            acc[n] += a;
        }
    }

    // wave reduce (64 lanes)
#pragma unroll
    for (int n = 0; n < NFLOW; ++n) {
#pragma unroll
        for (int off = 32; off > 0; off >>= 1)
            acc[n] += __shfl_down(acc[n], off, 64);
    }

    __shared__ float sacc[NFLOW][4];  // 4 waves per 256-thread block
    const int lane = threadIdx.x & 63;
    const int wid = threadIdx.x >> 6;
    if (lane == 0) {
#pragma unroll
        for (int n = 0; n < NFLOW; ++n) sacc[n][wid] = acc[n];
    }
    __syncthreads();
    if (threadIdx.x == 0) {
#pragma unroll
        for (int n = 0; n < NFLOW; ++n) {
            const float v = sacc[n][0] + sacc[n][1] + sacc[n][2] + sacc[n][3];
            atomicAdd(&sums[n], v);
        }
    }
}

// Kernel 2: psnr + weighted aggregation -> scalar
__global__ void psnr_finalize_kernel(const float* __restrict__ sums,
                                     float* __restrict__ out)
{
    if (threadIdx.x == 0 && blockIdx.x == 0) {
        double aggr = 0.0;
        for (int n = 0; n < NFLOW; ++n) {
            const double mse = (double)sums[n] / (3.0 * (double)HW);
            const double psnr = 10.0 * log10(255.0 * 255.0 / mse);
            double wgt = 1.0;
            for (int k = 0; k < NFLOW - n; ++k) wgt *= 0.85;
            aggr += psnr * wgt;
        }
        out[0] = (float)(-aggr);
    }
}

extern "C" void kernel_launch(void* const* d_in, const int* in_sizes, int n_in,
                              void* d_out, int out_size, void* d_ws, size_t ws_size,
                              hipStream_t stream) {
    const float* flow = (const float*)d_in[0];  // [5,1080,1920,2]
    const float* f1   = (const float*)d_in[1];  // [3,1080,1920]
    const float* f2   = (const float*)d_in[2];  // [3,1080,1920]
    float* out = (float*)d_out;
    float* sums = (float*)d_ws;                 // 5 floats

    hipMemsetAsync(sums, 0, NFLOW * sizeof(float), stream);

    const int threads = 256;
    const int blocks = 2048;
    psnr_partial_kernel<<<blocks, threads, 0, stream>>>(flow, f1, f2, sums);
    psnr_finalize_kernel<<<1, 64, 0, stream>>>(sums, out);
}